// Round 16
// baseline (186.138 us; speedup 1.0000x reference)
//
#include <hip/hip_runtime.h>
#include <stdint.h>
#include <math.h>

typedef unsigned short u16;
typedef __attribute__((ext_vector_type(8))) short short8;   // 8 bf16 (4 VGPRs)
typedef __attribute__((ext_vector_type(4))) short short4v;  // 4 bf16 (2 VGPRs)
typedef __attribute__((ext_vector_type(4))) float f32x4;

#define DEVFN static __device__ __forceinline__

DEVFN float bf2f(short b) {
  union { unsigned int i; float f; } u;
  u.i = ((unsigned int)(unsigned short)b) << 16;
  return u.f;
}
DEVFN short f2bf(float f) {
  union { float f; unsigned int i; } u; u.f = f;
  unsigned int r = u.i + 0x7fffu + ((u.i >> 16) & 1u);  // RNE
  return (short)(r >> 16);
}

DEVFN f32x4 mfma32(short8 a, short8 b, f32x4 c) {
  return __builtin_amdgcn_mfma_f32_16x16x32_bf16(a, b, c, 0, 0, 0);
}
DEVFN f32x4 mfma16(short4v a, short4v b, f32x4 c) {
#if defined(__HIP_DEVICE_COMPILE__)
  return __builtin_amdgcn_mfma_f32_16x16x16bf16_1k(a, b, c, 0, 0, 0);
#else
  (void)a; (void)b; return c;  // host stub, never executed
#endif
}

typedef const __attribute__((address_space(1))) unsigned int* gp_t;
typedef __attribute__((address_space(3))) unsigned int* lp_t;
typedef const __attribute__((address_space(3))) u16* lds_cp;
DEVFN void async_copy16(u16* lds, const u16* g) {
  __builtin_amdgcn_global_load_lds((gp_t)(const void*)g, (lp_t)(void*)lds, 16, 0, 0);
}
// tr-read: 16-lane group reads a 4x16 bf16 row-major tile (128B); lane passes
// subtile_base + (lane&15)*8 bytes; output lane = column (lane&15), elem j = row j.
DEVFN short4v tr_read16(const u16* p) {
  short4v r;
  asm volatile("ds_read_b64_tr_b16 %0, %1" : "=v"(r) : "v"((lds_cp)(const void*)p));
  return r;
}
DEVFN void raw_barrier() {
  asm volatile("" ::: "memory");
  __builtin_amdgcn_s_barrier();
  asm volatile("" ::: "memory");
}

// ---------------- mega-cast: 6 f32 buffers -> bf16 in ONE launch ----------------
// f32x4 units: h_in 1048576 | qaw 786432 | kvaw 294912 | qbw 1179648 | kvbw 524288
// | ow 1048576; cum 1048576,1835008,2129920,3309568,3833856,4882432. grid 19072.
__global__ void cast6_kernel(const float* __restrict__ s0, const float* __restrict__ s1,
                             const float* __restrict__ s2, const float* __restrict__ s3,
                             const float* __restrict__ s4, const float* __restrict__ s5,
                             u16* __restrict__ d0, u16* __restrict__ d1,
                             u16* __restrict__ d2, u16* __restrict__ d3,
                             u16* __restrict__ d4, u16* __restrict__ d5) {
  int i = blockIdx.x * blockDim.x + threadIdx.x;
  const float* s; u16* d; int off;
  if (i < 1048576)      { s = s0; d = d0; off = 0; }
  else if (i < 1835008) { s = s1; d = d1; off = 1048576; }
  else if (i < 2129920) { s = s2; d = d2; off = 1835008; }
  else if (i < 3309568) { s = s3; d = d3; off = 2129920; }
  else if (i < 3833856) { s = s4; d = d4; off = 3309568; }
  else                  { s = s5; d = d5; off = 3833856; }
  int j = i - off;
  f32x4 v = ((const f32x4*)s)[j];
  short4v o;
  o[0] = f2bf(v[0]); o[1] = f2bf(v[1]); o[2] = f2bf(v[2]); o[3] = f2bf(v[3]);
  ((short4v*)d)[j] = o;
}

// ---------------- fused dual RMSNorm: q rows + kv rows in ONE launch ----------------
__global__ void rmsnorm2_kernel(const u16* __restrict__ F,
                                const float* __restrict__ qln,
                                const float* __restrict__ kvln,
                                u16* __restrict__ qa, u16* __restrict__ ckvn) {
  const int bid = blockIdx.x, t = threadIdx.x;
  const bool isQ = bid < 2048;
  const int row = isQ ? bid : bid - 2048;
  const u16* in = (isQ ? F : F + 1536) + (size_t)row * 2112;
  u16* out = isQ ? (qa + (size_t)row * 1536) : (ckvn + (size_t)row * 512);
  const float* w = isQ ? qln : kvln;
  const int len = isQ ? 1536 : 512;
  const int nact = len >> 3;
  float ss = 0.f;
  short8 v = {};
  if (t < nact) {
    v = *(const short8*)(in + t * 8);
#pragma unroll
    for (int j = 0; j < 8; ++j) { float x = bf2f(v[j]); ss += x * x; }
  }
#pragma unroll
  for (int off = 1; off < 64; off <<= 1) ss += __shfl_xor(ss, off);
  __shared__ float red[3];
  if ((t & 63) == 0) red[t >> 6] = ss;
  __syncthreads();
  ss = red[0] + red[1] + red[2];
  float r = rsqrtf(ss / (float)len + 1e-6f);
  if (t < nact) {
    const float* wp = w + t * 8;
    short8 ov;
#pragma unroll
    for (int j = 0; j < 8; ++j) ov[j] = f2bf(bf2f(v[j]) * r * wp[j]);
    *(short8*)(out + t * 8) = ov;
  }
}

// ---------------- RoPE (interleaved-perm variant) ----------------
__global__ void rope_kernel(const u16* __restrict__ q, const u16* __restrict__ ckv,
                            int cstride,
                            const int* __restrict__ pos_ids,
                            u16* __restrict__ qpe, u16* __restrict__ kpe) {
  const int row = blockIdx.x;
  const int t = threadIdx.x;
  const float pos = (float)pos_ids[row];
  const float L2TH = 13.287712379549449f;  // log2(10000)
  if (t < 32) {
    int i = t;
    float inv = exp2f(-L2TH * (float)i / 32.0f);
    float sv, cv; sincosf(pos * inv, &sv, &cv);
    float x0 = bf2f(ckv[(size_t)row * cstride + 512 + 2 * i]);
    float x1 = bf2f(ckv[(size_t)row * cstride + 512 + 2 * i + 1]);
    kpe[(size_t)row * 64 + i]      = (u16)f2bf(x0 * cv - x1 * sv);
    kpe[(size_t)row * 64 + 32 + i] = (u16)f2bf(x1 * cv + x0 * sv);
  }
#pragma unroll
  for (int j = 0; j < 8; ++j) {
    int idx = t + 64 * j;
    int hh = idx >> 5, i = idx & 31;
    float inv = exp2f(-L2TH * (float)i / 32.0f);
    float sv, cv; sincosf(pos * inv, &sv, &cv);
    const u16* base = q + (size_t)row * 3072 + hh * 192 + 128;
    float x0 = bf2f(base[2 * i]), x1 = bf2f(base[2 * i + 1]);
    u16* ob = qpe + ((size_t)row * 16 + hh) * 64;
    ob[i]      = (u16)f2bf(x0 * cv - x1 * sv);
    ob[32 + i] = (u16)f2bf(x1 * cv + x0 * sv);
  }
}

// ---------------- shared GEMM body (2-barrier, 2-buffer, proven) ----------------
// R14 lesson baked in: stage() only at END of iteration, never between the
// waitcnt-asm and the compute ds_reads (compiler inserts a vmcnt(0) drain).
template <int BM, int BN, bool OUT_F32>
DEVFN void gemm_body(const u16* A, const u16* B, void* C,
                     int K, int ldc, int m0, int n0, int tid) {
  constexpr int ACH = BM / 32;
  constexpr int BCH = BN / 32;
  constexpr int MI  = BM / 32;
  constexpr int NI  = BN / 32;
  constexpr int LOADS = ACH + BCH;
  __shared__ u16 As[2][BM * 64];
  __shared__ u16 Bs[2][BN * 64];
  const int w = tid >> 6, l = tid & 63;
  const int lq = l & 15, lg = l >> 4;
  const int wm = (w >> 1) * (BM / 2);
  const int wn = (w & 1) * (BN / 2);

  const u16* srcA[ACH]; int dstA[ACH];
#pragma unroll
  for (int i = 0; i < ACH; ++i) {
    int c = i * 256 + tid;
    int row = c >> 3, pc = c & 7;
    int lc = pc ^ (row & 7);
    srcA[i] = A + (size_t)(m0 + row) * K + lc * 8;
    dstA[i] = c * 8;
  }
  const u16* srcB[BCH]; int dstB[BCH];
#pragma unroll
  for (int i = 0; i < BCH; ++i) {
    int c = i * 256 + tid;
    int row = c >> 3, pc = c & 7;
    int lc = pc ^ (row & 7);
    srcB[i] = B + (size_t)(n0 + row) * K + lc * 8;
    dstB[i] = c * 8;
  }

  auto stage = [&](int buf) {
#pragma unroll
    for (int i = 0; i < ACH; ++i) {
      async_copy16(&As[buf][dstA[i]], srcA[i]);
      srcA[i] += 64;
    }
#pragma unroll
    for (int i = 0; i < BCH; ++i) {
      async_copy16(&Bs[buf][dstB[i]], srcB[i]);
      srcB[i] += 64;
    }
  };

  f32x4 acc[MI][NI];
#pragma unroll
  for (int i = 0; i < MI; ++i)
#pragma unroll
    for (int j = 0; j < NI; ++j) acc[i][j] = (f32x4){0.f, 0.f, 0.f, 0.f};

  const int nt = K >> 6;
  stage(0);
  if (nt > 1) stage(1);

  for (int t = 0; t < nt; ++t) {
    if (t + 1 < nt) {
      if constexpr (LOADS == 4)      asm volatile("s_waitcnt vmcnt(4)" ::: "memory");
      else if constexpr (LOADS == 6) asm volatile("s_waitcnt vmcnt(6)" ::: "memory");
      else if constexpr (LOADS == 7) asm volatile("s_waitcnt vmcnt(7)" ::: "memory");
      else                           asm volatile("s_waitcnt vmcnt(8)" ::: "memory");
    } else {
      asm volatile("s_waitcnt vmcnt(0)" ::: "memory");
    }
    raw_barrier();

    const int buf = t & 1;
#pragma unroll
    for (int ks = 0; ks < 2; ++ks) {
      short8 af[MI], bfr[NI];
#pragma unroll
      for (int mi = 0; mi < MI; ++mi) {
        int row = wm + mi * 16 + lq;
        int ch = ((ks << 2) | lg) ^ (row & 7);
        af[mi] = *(const short8*)&As[buf][row * 64 + ch * 8];
      }
#pragma unroll
      for (int ni = 0; ni < NI; ++ni) {
        int row = wn + ni * 16 + lq;
        int ch = ((ks << 2) | lg) ^ (row & 7);
        bfr[ni] = *(const short8*)&Bs[buf][row * 64 + ch * 8];
      }
#pragma unroll
      for (int mi = 0; mi < MI; ++mi)
#pragma unroll
        for (int ni = 0; ni < NI; ++ni)
          acc[mi][ni] = mfma32(af[mi], bfr[ni], acc[mi][ni]);
    }

    raw_barrier();
    if (t + 2 < nt) stage(buf);   // END of iter (R14 lesson)
  }

#pragma unroll
  for (int mi = 0; mi < MI; ++mi) {
#pragma unroll
    for (int ni = 0; ni < NI; ++ni) {
      int col = n0 + wn + ni * 16 + lq;
#pragma unroll
      for (int r = 0; r < 4; ++r) {
        int rowm = m0 + wm + mi * 16 + lg * 4 + r;
        if constexpr (OUT_F32)
          ((float*)C)[(size_t)rowm * ldc + col] = acc[mi][ni][r];
        else
          ((u16*)C)[(size_t)rowm * ldc + col] = (u16)f2bf(acc[mi][ni][r]);
      }
    }
  }
}

// ---------------- standalone GEMM (G1f / G5) ----------------
template <int BM, int BN, bool OUT_F32, int TAG>
__global__ __launch_bounds__(256) void gemm_bt(const u16* __restrict__ A,
                                               const u16* __restrict__ B,
                                               void* __restrict__ C,
                                               int M, int N, int K, int ldc) {
  const int f = blockIdx.x + gridDim.x * blockIdx.y;
  const int nwg = gridDim.x * gridDim.y;
  const int swz = (f & 7) * (nwg >> 3) + (f >> 3);
  const int bx = swz % gridDim.x, by = swz / gridDim.x;
  gemm_body<BM, BN, OUT_F32>(A, B, C, K, ldc, by * BM, bx * BN, threadIdx.x);
}

// ---------------- merged G2+G4: one 1792-block launch, BN=64 ----------------
// work id < 768: G2 (48x16 tiles of qa@K1536 x Wqb -> qbuf[ldc 3072])
// else:          G4 (64x16 tiles of ckvn@K512 x Wkvb -> kvb[ldc 4096])
// 48 KB LDS -> 3 blocks/CU resident (was 2 at separate 512-block launches):
// third block's compute covers the other two's staging stalls; one less launch.
__global__ __launch_bounds__(256) void gemm_g24(const u16* __restrict__ qa,
                                                const u16* __restrict__ Wqb,
                                                u16* __restrict__ qbuf,
                                                const u16* __restrict__ ckvn,
                                                const u16* __restrict__ Wkvb,
                                                u16* __restrict__ kvb) {
  const int f = blockIdx.x;
  const int swz = (f & 7) * (1792 >> 3) + (f >> 3);   // XCD-bijective, 1792%8==0
  if (swz < 768) {
    const int bx = swz % 48, by = swz / 48;
    gemm_body<128, 64, false>(qa, Wqb, qbuf, 1536, 3072, by * 128, bx * 64, threadIdx.x);
  } else {
    const int s2 = swz - 768;
    const int bx = s2 % 64, by = s2 / 64;
    gemm_body<128, 64, false>(ckvn, Wkvb, kvb, 512, 4096, by * 128, bx * 64, threadIdx.x);
  }
}

// ---------------- causal flash attention: in-block split-K, spill-free (R9) ----------------
__global__ __launch_bounds__(512, 4) void attn_kernel(const u16* __restrict__ q,
                                                      const u16* __restrict__ qpe,
                                                      const u16* __restrict__ kv,
                                                      const u16* __restrict__ kpe,
                                                      u16* __restrict__ o) {
  __shared__ u16 Ks[2][2][32 * 192];   // [buf][team] 12 KB each -> 48 KB
  __shared__ u16 Vs[2][2][32 * 128];   // [buf][team]  8 KB each -> 32 KB
  const int S = 1024;
  const int tid = threadIdx.x;
  const int w = tid >> 6, l = tid & 63;
  const int team = w >> 2, wt = w & 3;
  const int lq = l & 15, lg = l >> 4;
  const int h = blockIdx.y, b = blockIdx.z;
  const int chunk = b ? (15 - (int)blockIdx.x) : (int)blockIdx.x;
  const int q0 = chunk * 64 + wt * 16;
  const int nkt = chunk + 1;            // 32-row tiles per team
  const size_t qrow = (size_t)b * S + q0 + lq;

  short8 qf[6];
#pragma unroll
  for (int c = 0; c < 4; ++c)
    qf[c] = *(const short8*)(q + qrow * 3072 + h * 192 + c * 32 + lg * 8);
#pragma unroll
  for (int c = 0; c < 2; ++c)
    qf[4 + c] = *(const short8*)(qpe + (qrow * 16 + h) * 64 + c * 32 + lg * 8);

  const size_t gb = (size_t)b * S + 32 * team;   // team t starts at k-row 32t
  const u16* srcK[3]; int strK[3];
#pragma unroll
  for (int j = 0; j < 3; ++j) {
    int n = wt * 192 + j * 64 + l;         // K chunk id within team, 0..767
    int row = (n * 2731) >> 16;            // n / 24
    int pc = n - row * 24;
    int lc = (pc & ~7) | ((pc & 7) ^ (row & 7));   // inverse swizzle on source
    if (lc < 16) { srcK[j] = kv + (gb + row) * 4096 + h * 256 + lc * 8; strK[j] = 64 * 4096; }
    else         { srcK[j] = kpe + (gb + row) * 64 + (lc - 16) * 8;     strK[j] = 64 * 64; }
  }
  const u16* srcV[2];
#pragma unroll
  for (int j = 0; j < 2; ++j) {
    int n = wt * 128 + j * 64 + l;         // V chunk id within team, 0..511
    int dsub = n >> 6, m = n & 63;
    int ksub = m >> 3, r = (m >> 1) & 3, half = m & 1;
    srcV[j] = kv + (gb + ksub * 4 + r) * 4096 + h * 256 + 128 + dsub * 16 + half * 8;
  }

  auto stage = [&](int buf) {
#pragma unroll
    for (int j = 0; j < 3; ++j) {
      async_copy16(&Ks[buf][team][(wt * 192 + j * 64) * 8], srcK[j]);
      srcK[j] += strK[j];
    }
#pragma unroll
    for (int j = 0; j < 2; ++j) {
      async_copy16(&Vs[buf][team][(wt * 128 + j * 64) * 8], srcV[j]);
      srcV[j] += 64 * 4096;
    }
  };

  const float scl = 0.07216878364870323f * 1.4426950408889634f;  // 192^-0.5 * log2e
  float m2 = -INFINITY, lsum = 0.f;
  f32x4 oac[8];
#pragma unroll
  for (int dt = 0; dt < 8; ++dt) oac[dt] = (f32x4){0.f, 0.f, 0.f, 0.f};

  const int e0 = (lg ^ (lq & 7)) << 4;
  const int vbase = lg * 64 + lq * 4;

  stage(0);
  asm volatile("s_waitcnt vmcnt(0)" ::: "memory");
  __syncthreads();

  int buf = 0;
  for (int i = 0; i < nkt; ++i) {
    if (i + 1 < nkt) stage(buf ^ 1);
    const int kbase = (2 * i + team) * 32;

    if (kbase <= q0 + 15) {   // wave-uniform: skip fully-masked tiles
      const char* kb = (const char*)&Ks[buf][team][0];
      f32x4 sac0, sac1;
#pragma unroll
      for (int kt2 = 0; kt2 < 2; ++kt2) {
        int a0 = (kt2 * 16 + lq) * 384 + e0;
        int a1 = a0 ^ 64;
        f32x4 s = (f32x4){0.f, 0.f, 0.f, 0.f};
        s = mfma32(*(const short8*)(kb + a0),       qf[0], s);
        s = mfma32(*(const short8*)(kb + a1),       qf[1], s);
        s = mfma32(*(const short8*)(kb + a0 + 128), qf[2], s);
        s = mfma32(*(const short8*)(kb + a1 + 128), qf[3], s);
        s = mfma32(*(const short8*)(kb + a0 + 256), qf[4], s);
        s = mfma32(*(const short8*)(kb + a1 + 256), qf[5], s);
        if (kt2 == 0) sac0 = s; else sac1 = s;
      }

      const int qi = q0 + lq;
      const int kb0 = kbase + lg * 4;
      float s2[8];
#pragma unroll
      for (int r = 0; r < 4; ++r) {
        s2[r]     = (kb0 + r      <= qi) ? sac0[r] * scl : -INFINITY;
        s2[4 + r] = (kb0 + 16 + r <= qi) ? sac1[r] * scl : -INFINITY;
      }
      float mt = fmaxf(fmaxf(fmaxf(s2[0], s2[1]), fmaxf(s2[2], s2[3])),
                       fmaxf(fmaxf(s2[4], s2[5]), fmaxf(s2[6], s2[7])));
      mt = fmaxf(mt, __shfl_xor(mt, 16));
      mt = fmaxf(mt, __shfl_xor(mt, 32));
      float mnew = fmaxf(m2, mt);
      float resc = exp2f(m2 - mnew);
      float psum = 0.f;
#pragma unroll
      for (int r = 0; r < 8; ++r) { s2[r] = exp2f(s2[r] - mnew); psum += s2[r]; }
      psum += __shfl_xor(psum, 16);
      psum += __shfl_xor(psum, 32);
      lsum = lsum * resc + psum;
      m2 = mnew;
      short4v pf0, pf1;
#pragma unroll
      for (int r = 0; r < 4; ++r) { pf0[r] = f2bf(s2[r]); pf1[r] = f2bf(s2[4 + r]); }

      // ---- PV in 2 halves: vf[4][2] = 16 VGPRs peak ----
#pragma unroll
      for (int hf = 0; hf < 2; ++hf) {
        short4v vf[4][2];
#pragma unroll
        for (int dd = 0; dd < 4; ++dd)
#pragma unroll
          for (int kt2 = 0; kt2 < 2; ++kt2)
            vf[dd][kt2] = tr_read16(&Vs[buf][team][vbase + (hf * 4 + dd) * 512 + kt2 * 256]);
        asm volatile("s_waitcnt lgkmcnt(0)" ::: "memory");
        __builtin_amdgcn_sched_barrier(0);
#pragma unroll
        for (int dd = 0; dd < 4; ++dd) {
          const int dt = hf * 4 + dd;
          f32x4 t = oac[dt];
          t[0] *= resc; t[1] *= resc; t[2] *= resc; t[3] *= resc;
          t = mfma16(vf[dd][0], pf0, t);
          t = mfma16(vf[dd][1], pf1, t);
          oac[dt] = t;
        }
      }
    }

    asm volatile("s_waitcnt vmcnt(0)" ::: "memory");
    __syncthreads();
    buf ^= 1;
  }

  // ---- split-K merge via LDS (K/V buffers dead) ----
  float* MO = (float*)&Ks[0][0][0];     // 64 x 129 f32 (padded)
  float* MS = (float*)&Vs[0][0][0];     // 64 x 2 f32 stats
  const int qr = wt * 16 + lq;
  if (team == 1) {
#pragma unroll
    for (int dt = 0; dt < 8; ++dt)
#pragma unroll
      for (int r = 0; r < 4; ++r)
        MO[qr * 129 + dt * 16 + lg * 4 + r] = oac[dt][r];
    if (lg == 0) { MS[qr * 2] = m2; MS[qr * 2 + 1] = lsum; }
  }
  __syncthreads();
  if (team == 0) {
    float m1 = MS[qr * 2], l1 = MS[qr * 2 + 1];
    float mn = fmaxf(m2, m1);
    float a0 = exp2f(m2 - mn), a1 = exp2f(m1 - mn);
    float inv = 1.f / (lsum * a0 + l1 * a1);
#pragma unroll
    for (int dt = 0; dt < 8; ++dt)
#pragma unroll
      for (int r = 0; r < 4; ++r) {
        float val = (oac[dt][r] * a0 + MO[qr * 129 + dt * 16 + lg * 4 + r] * a1) * inv;
        o[((size_t)b * S + q0 + lq) * 2048 + h * 128 + dt * 16 + lg * 4 + r] = (u16)f2bf(val);
      }
  }
}

// ---------------- host launcher ----------------
extern "C" void kernel_launch(void* const* d_in, const int* in_sizes, int n_in,
                              void* d_out, int out_size, void* d_ws, size_t ws_size,
                              hipStream_t stream) {
  const float* h_in  = (const float*)d_in[0];
  const int*   pos   = (const int*)d_in[1];
  const float* qaw   = (const float*)d_in[2];
  const float* qaln  = (const float*)d_in[3];
  const float* qbw   = (const float*)d_in[4];
  const float* kvaw  = (const float*)d_in[5];
  const float* kvaln = (const float*)d_in[6];
  const float* kvbw  = (const float*)d_in[7];
  const float* ow    = (const float*)d_in[8];
  float* out = (float*)d_out;

  const int M = 2048;  // B*S
  char* p = (char*)d_ws;
  auto alloc = [&](size_t bytes) {
    char* r = p;
    p += (bytes + 255) & ~(size_t)255;
    return (u16*)r;
  };
  u16* h_bf   = alloc((size_t)M * 2048 * 2);       // hidden bf16; attno overlay later
  u16* Wfused = alloc((size_t)2112 * 2048 * 2);    // [q_a_w ; kv_a_w] rows, K=2048
  u16* Wqb    = alloc((size_t)3072 * 1536 * 2);
  u16* Wkvb   = alloc((size_t)4096 * 512 * 2);
  u16* OW     = alloc((size_t)2048 * 2048 * 2);    // o_w bf16 (dedicated, cast upfront)
  u16* F      = alloc((size_t)M * 2112 * 2);       // fused G1 out: q_a | ckv
  u16* qbuf   = alloc((size_t)M * 3072 * 2);
  u16* kvb    = alloc((size_t)M * 4096 * 2);
  u16* qpe    = alloc((size_t)M * 16 * 64 * 2);
  u16* kpe    = alloc((size_t)M * 64 * 2);
  // overlays (audited): Wfused dead after G1f -> qa/ckvn; h_bf dead -> attno.
  u16* qa    = Wfused;                             // M x 1536
  u16* ckvn  = Wfused + (size_t)1536 * 2048;       // M x 512
  u16* attno = h_bf;                               // M x 2048

  dim3 blk(256);

  // 1) ONE launch casts hidden + ALL weights (6 segments)
  cast6_kernel<<<19072, blk, 0, stream>>>(h_in, qaw, kvaw, qbw, kvbw, ow,
                                          h_bf, Wfused, Wfused + (size_t)1536 * 2048,
                                          Wqb, Wkvb, OW);

  // 2) fused G1+G3
  gemm_bt<128, 64, false, 1><<<dim3(33, 16), blk, 0, stream>>>(h_bf, Wfused, F, M, 2112, 2048, 2112);

  // 3) both RMSNorms in one launch
  rmsnorm2_kernel<<<4096, 192, 0, stream>>>(F, qaln, kvaln, qa, ckvn);

  // 4+5) merged G2+G4: 1792 blocks, 3 resident/CU
  gemm_g24<<<1792, blk, 0, stream>>>(qa, Wqb, qbuf, ckvn, Wkvb, kvb);

  // 6) RoPE
  rope_kernel<<<2048, 64, 0, stream>>>(qbuf, F + 1536, 2112, pos, qpe, kpe);

  // 7) attention
  attn_kernel<<<dim3(16, 16, 2), 512, 0, stream>>>(qbuf, qpe, kvb, kpe, attno);

  // 8) output projection
  gemm_bt<128, 64, true, 5><<<dim3(32, 16), blk, 0, stream>>>(attno, OW, out, M, 2048, 2048, 2048);
}

// Round 17
// 185.757 us; speedup vs baseline: 1.0021x; 1.0021x over previous
//
#include <hip/hip_runtime.h>
#include <stdint.h>
#include <math.h>

typedef unsigned short u16;
typedef __attribute__((ext_vector_type(8))) short short8;   // 8 bf16 (4 VGPRs)
typedef __attribute__((ext_vector_type(4))) short short4v;  // 4 bf16 (2 VGPRs)
typedef __attribute__((ext_vector_type(4))) float f32x4;

#define DEVFN static __device__ __forceinline__

DEVFN float bf2f(short b) {
  union { unsigned int i; float f; } u;
  u.i = ((unsigned int)(unsigned short)b) << 16;
  return u.f;
}
DEVFN short f2bf(float f) {
  union { float f; unsigned int i; } u; u.f = f;
  unsigned int r = u.i + 0x7fffu + ((u.i >> 16) & 1u);  // RNE
  return (short)(r >> 16);
}

DEVFN f32x4 mfma32(short8 a, short8 b, f32x4 c) {
  return __builtin_amdgcn_mfma_f32_16x16x32_bf16(a, b, c, 0, 0, 0);
}
DEVFN f32x4 mfma16(short4v a, short4v b, f32x4 c) {
#if defined(__HIP_DEVICE_COMPILE__)
  return __builtin_amdgcn_mfma_f32_16x16x16bf16_1k(a, b, c, 0, 0, 0);
#else
  (void)a; (void)b; return c;  // host stub, never executed
#endif
}

typedef const __attribute__((address_space(1))) unsigned int* gp_t;
typedef __attribute__((address_space(3))) unsigned int* lp_t;
typedef const __attribute__((address_space(3))) u16* lds_cp;
DEVFN void async_copy16(u16* lds, const u16* g) {
  __builtin_amdgcn_global_load_lds((gp_t)(const void*)g, (lp_t)(void*)lds, 16, 0, 0);
}
// tr-read: 16-lane group reads a 4x16 bf16 row-major tile (128B); lane passes
// subtile_base + (lane&15)*8 bytes; output lane = column (lane&15), elem j = row j.
DEVFN short4v tr_read16(const u16* p) {
  short4v r;
  asm volatile("ds_read_b64_tr_b16 %0, %1" : "=v"(r) : "v"((lds_cp)(const void*)p));
  return r;
}
DEVFN void raw_barrier() {
  asm volatile("" ::: "memory");
  __builtin_amdgcn_s_barrier();
  asm volatile("" ::: "memory");
}

// ---------------- mega-cast: 6 f32 buffers -> bf16 in ONE launch ----------------
// f32x4 units: h_in 1048576 | qaw 786432 | kvaw 294912 | qbw 1179648 | kvbw 524288
// | ow 1048576; cum 1048576,1835008,2129920,3309568,3833856,4882432. grid 19072.
__global__ void cast6_kernel(const float* __restrict__ s0, const float* __restrict__ s1,
                             const float* __restrict__ s2, const float* __restrict__ s3,
                             const float* __restrict__ s4, const float* __restrict__ s5,
                             u16* __restrict__ d0, u16* __restrict__ d1,
                             u16* __restrict__ d2, u16* __restrict__ d3,
                             u16* __restrict__ d4, u16* __restrict__ d5) {
  int i = blockIdx.x * blockDim.x + threadIdx.x;
  const float* s; u16* d; int off;
  if (i < 1048576)      { s = s0; d = d0; off = 0; }
  else if (i < 1835008) { s = s1; d = d1; off = 1048576; }
  else if (i < 2129920) { s = s2; d = d2; off = 1835008; }
  else if (i < 3309568) { s = s3; d = d3; off = 2129920; }
  else if (i < 3833856) { s = s4; d = d4; off = 3309568; }
  else                  { s = s5; d = d5; off = 3833856; }
  int j = i - off;
  f32x4 v = ((const f32x4*)s)[j];
  short4v o;
  o[0] = f2bf(v[0]); o[1] = f2bf(v[1]); o[2] = f2bf(v[2]); o[3] = f2bf(v[3]);
  ((short4v*)d)[j] = o;
}

// ---------------- fused dual RMSNorm: q rows + kv rows in ONE launch ----------------
__global__ void rmsnorm2_kernel(const u16* __restrict__ F,
                                const float* __restrict__ qln,
                                const float* __restrict__ kvln,
                                u16* __restrict__ qa, u16* __restrict__ ckvn) {
  const int bid = blockIdx.x, t = threadIdx.x;
  const bool isQ = bid < 2048;
  const int row = isQ ? bid : bid - 2048;
  const u16* in = (isQ ? F : F + 1536) + (size_t)row * 2112;
  u16* out = isQ ? (qa + (size_t)row * 1536) : (ckvn + (size_t)row * 512);
  const float* w = isQ ? qln : kvln;
  const int len = isQ ? 1536 : 512;
  const int nact = len >> 3;
  float ss = 0.f;
  short8 v = {};
  if (t < nact) {
    v = *(const short8*)(in + t * 8);
#pragma unroll
    for (int j = 0; j < 8; ++j) { float x = bf2f(v[j]); ss += x * x; }
  }
#pragma unroll
  for (int off = 1; off < 64; off <<= 1) ss += __shfl_xor(ss, off);
  __shared__ float red[3];
  if ((t & 63) == 0) red[t >> 6] = ss;
  __syncthreads();
  ss = red[0] + red[1] + red[2];
  float r = rsqrtf(ss / (float)len + 1e-6f);
  if (t < nact) {
    const float* wp = w + t * 8;
    short8 ov;
#pragma unroll
    for (int j = 0; j < 8; ++j) ov[j] = f2bf(bf2f(v[j]) * r * wp[j]);
    *(short8*)(out + t * 8) = ov;
  }
}

// ---------------- RoPE (interleaved-perm variant) ----------------
__global__ void rope_kernel(const u16* __restrict__ q, const u16* __restrict__ ckv,
                            int cstride,
                            const int* __restrict__ pos_ids,
                            u16* __restrict__ qpe, u16* __restrict__ kpe) {
  const int row = blockIdx.x;
  const int t = threadIdx.x;
  const float pos = (float)pos_ids[row];
  const float L2TH = 13.287712379549449f;  // log2(10000)
  if (t < 32) {
    int i = t;
    float inv = exp2f(-L2TH * (float)i / 32.0f);
    float sv, cv; sincosf(pos * inv, &sv, &cv);
    float x0 = bf2f(ckv[(size_t)row * cstride + 512 + 2 * i]);
    float x1 = bf2f(ckv[(size_t)row * cstride + 512 + 2 * i + 1]);
    kpe[(size_t)row * 64 + i]      = (u16)f2bf(x0 * cv - x1 * sv);
    kpe[(size_t)row * 64 + 32 + i] = (u16)f2bf(x1 * cv + x0 * sv);
  }
#pragma unroll
  for (int j = 0; j < 8; ++j) {
    int idx = t + 64 * j;
    int hh = idx >> 5, i = idx & 31;
    float inv = exp2f(-L2TH * (float)i / 32.0f);
    float sv, cv; sincosf(pos * inv, &sv, &cv);
    const u16* base = q + (size_t)row * 3072 + hh * 192 + 128;
    float x0 = bf2f(base[2 * i]), x1 = bf2f(base[2 * i + 1]);
    u16* ob = qpe + ((size_t)row * 16 + hh) * 64;
    ob[i]      = (u16)f2bf(x0 * cv - x1 * sv);
    ob[32 + i] = (u16)f2bf(x1 * cv + x0 * sv);
  }
}

// ---------------- GEMM (2-barrier, 2-buffer): G2 (BN=96) / G4 (BN=128) ----------------
template <int BM, int BN, bool OUT_F32, int TAG>
__global__ __launch_bounds__(256) void gemm_bt(const u16* __restrict__ A,
                                               const u16* __restrict__ B,
                                               void* __restrict__ C,
                                               int M, int N, int K, int ldc) {
  constexpr int ACH = BM / 32;
  constexpr int BCH = BN / 32;
  constexpr int MI  = BM / 32;
  constexpr int NI  = BN / 32;
  constexpr int LOADS = ACH + BCH;
  __shared__ u16 As[2][BM * 64];
  __shared__ u16 Bs[2][BN * 64];
  const int tid = threadIdx.x;
  const int w = tid >> 6, l = tid & 63;
  const int lq = l & 15, lg = l >> 4;
  const int wm = (w >> 1) * (BM / 2);
  const int wn = (w & 1) * (BN / 2);

  const int f = blockIdx.x + gridDim.x * blockIdx.y;
  const int nwg = gridDim.x * gridDim.y;
  const int swz = (f & 7) * (nwg >> 3) + (f >> 3);
  const int bx = swz % gridDim.x, by = swz / gridDim.x;
  const int m0 = by * BM, n0 = bx * BN;

  const u16* srcA[ACH]; int dstA[ACH];
#pragma unroll
  for (int i = 0; i < ACH; ++i) {
    int c = i * 256 + tid;
    int row = c >> 3, pc = c & 7;
    int lc = pc ^ (row & 7);
    srcA[i] = A + (size_t)(m0 + row) * K + lc * 8;
    dstA[i] = c * 8;
  }
  const u16* srcB[BCH]; int dstB[BCH];
#pragma unroll
  for (int i = 0; i < BCH; ++i) {
    int c = i * 256 + tid;
    int row = c >> 3, pc = c & 7;
    int lc = pc ^ (row & 7);
    srcB[i] = B + (size_t)(n0 + row) * K + lc * 8;
    dstB[i] = c * 8;
  }

  auto stage = [&](int buf) {
#pragma unroll
    for (int i = 0; i < ACH; ++i) {
      async_copy16(&As[buf][dstA[i]], srcA[i]);
      srcA[i] += 64;
    }
#pragma unroll
    for (int i = 0; i < BCH; ++i) {
      async_copy16(&Bs[buf][dstB[i]], srcB[i]);
      srcB[i] += 64;
    }
  };

  f32x4 acc[MI][NI];
#pragma unroll
  for (int i = 0; i < MI; ++i)
#pragma unroll
    for (int j = 0; j < NI; ++j) acc[i][j] = (f32x4){0.f, 0.f, 0.f, 0.f};

  const int nt = K >> 6;
  stage(0);
  if (nt > 1) stage(1);

  for (int t = 0; t < nt; ++t) {
    if (t + 1 < nt) {
      if constexpr (LOADS == 4)      asm volatile("s_waitcnt vmcnt(4)" ::: "memory");
      else if constexpr (LOADS == 6) asm volatile("s_waitcnt vmcnt(6)" ::: "memory");
      else if constexpr (LOADS == 7) asm volatile("s_waitcnt vmcnt(7)" ::: "memory");
      else                           asm volatile("s_waitcnt vmcnt(8)" ::: "memory");
    } else {
      asm volatile("s_waitcnt vmcnt(0)" ::: "memory");
    }
    raw_barrier();

    const int buf = t & 1;
#pragma unroll
    for (int ks = 0; ks < 2; ++ks) {
      short8 af[MI], bfr[NI];
#pragma unroll
      for (int mi = 0; mi < MI; ++mi) {
        int row = wm + mi * 16 + lq;
        int ch = ((ks << 2) | lg) ^ (row & 7);
        af[mi] = *(const short8*)&As[buf][row * 64 + ch * 8];
      }
#pragma unroll
      for (int ni = 0; ni < NI; ++ni) {
        int row = wn + ni * 16 + lq;
        int ch = ((ks << 2) | lg) ^ (row & 7);
        bfr[ni] = *(const short8*)&Bs[buf][row * 64 + ch * 8];
      }
#pragma unroll
      for (int mi = 0; mi < MI; ++mi)
#pragma unroll
        for (int ni = 0; ni < NI; ++ni)
          acc[mi][ni] = mfma32(af[mi], bfr[ni], acc[mi][ni]);
    }

    raw_barrier();
    if (t + 2 < nt) stage(buf);
  }

#pragma unroll
  for (int mi = 0; mi < MI; ++mi) {
#pragma unroll
    for (int ni = 0; ni < NI; ++ni) {
      int col = n0 + wn + ni * 16 + lq;
#pragma unroll
      for (int r = 0; r < 4; ++r) {
        int rowm = m0 + wm + mi * 16 + lg * 4 + r;
        if constexpr (OUT_F32)
          ((float*)C)[(size_t)rowm * ldc + col] = acc[mi][ni][r];
        else
          ((u16*)C)[(size_t)rowm * ldc + col] = (u16)f2bf(acc[mi][ni][r]);
      }
    }
  }
}

// ---------------- GEMM (1-barrier, 3-buffer): G1f / G5 ----------------
// R13-proven ordering: stage(t+1) is issued BEFORE the vmcnt(6), so the
// explicit waitcnt sits between the LDS-DMA issue and the compute ds_reads
// (R14 lesson: the reverse order triggers a compiler vmcnt(0) drain).
template <int BM, int BN, bool OUT_F32, int TAG>
__global__ __launch_bounds__(256) void gemm_bt3(const u16* __restrict__ A,
                                                const u16* __restrict__ B,
                                                void* __restrict__ C,
                                                int M, int N, int K, int ldc) {
  constexpr int ACH = BM / 32;
  constexpr int BCH = BN / 32;
  constexpr int MI  = BM / 32;
  constexpr int NI  = BN / 32;
  constexpr int LOADS = ACH + BCH;
  static_assert(LOADS == 6, "sized for BM128/BN64 (72 KB LDS, 2 blocks/CU)");
  __shared__ u16 As[3][BM * 64];    // 48 KB
  __shared__ u16 Bs[3][BN * 64];    // 24 KB
  const int tid = threadIdx.x;
  const int w = tid >> 6, l = tid & 63;
  const int lq = l & 15, lg = l >> 4;
  const int wm = (w >> 1) * (BM / 2);
  const int wn = (w & 1) * (BN / 2);

  const int f = blockIdx.x + gridDim.x * blockIdx.y;
  const int nwg = gridDim.x * gridDim.y;
  const int swz = (f & 7) * (nwg >> 3) + (f >> 3);
  const int bx = swz % gridDim.x, by = swz / gridDim.x;
  const int m0 = by * BM, n0 = bx * BN;

  const u16* srcA[ACH]; int dstA[ACH];
#pragma unroll
  for (int i = 0; i < ACH; ++i) {
    int c = i * 256 + tid;
    int row = c >> 3, pc = c & 7;
    int lc = pc ^ (row & 7);
    srcA[i] = A + (size_t)(m0 + row) * K + lc * 8;
    dstA[i] = c * 8;
  }
  const u16* srcB[BCH]; int dstB[BCH];
#pragma unroll
  for (int i = 0; i < BCH; ++i) {
    int c = i * 256 + tid;
    int row = c >> 3, pc = c & 7;
    int lc = pc ^ (row & 7);
    srcB[i] = B + (size_t)(n0 + row) * K + lc * 8;
    dstB[i] = c * 8;
  }

  auto stage = [&](int buf) {
#pragma unroll
    for (int i = 0; i < ACH; ++i) {
      async_copy16(&As[buf][dstA[i]], srcA[i]);
      srcA[i] += 64;
    }
#pragma unroll
    for (int i = 0; i < BCH; ++i) {
      async_copy16(&Bs[buf][dstB[i]], srcB[i]);
      srcB[i] += 64;
    }
  };

  f32x4 acc[MI][NI];
#pragma unroll
  for (int i = 0; i < MI; ++i)
#pragma unroll
    for (int j = 0; j < NI; ++j) acc[i][j] = (f32x4){0.f, 0.f, 0.f, 0.f};

  const int nt = K >> 6;
  stage(0);

  for (int t = 0; t < nt; ++t) {
    if (t + 1 < nt) {
      stage((t + 1) % 3);                                   // tile t+1
      asm volatile("s_waitcnt vmcnt(6)" ::: "memory");      // tile t landed
    } else {
      asm volatile("s_waitcnt vmcnt(0)" ::: "memory");
    }
    raw_barrier();                                           // ONE barrier/iter

    const int buf = t % 3;
#pragma unroll
    for (int ks = 0; ks < 2; ++ks) {
      short8 af[MI], bfr[NI];
#pragma unroll
      for (int mi = 0; mi < MI; ++mi) {
        int row = wm + mi * 16 + lq;
        int ch = ((ks << 2) | lg) ^ (row & 7);
        af[mi] = *(const short8*)&As[buf][row * 64 + ch * 8];
      }
#pragma unroll
      for (int ni = 0; ni < NI; ++ni) {
        int row = wn + ni * 16 + lq;
        int ch = ((ks << 2) | lg) ^ (row & 7);
        bfr[ni] = *(const short8*)&Bs[buf][row * 64 + ch * 8];
      }
#pragma unroll
      for (int mi = 0; mi < MI; ++mi)
#pragma unroll
        for (int ni = 0; ni < NI; ++ni)
          acc[mi][ni] = mfma32(af[mi], bfr[ni], acc[mi][ni]);
    }
  }

#pragma unroll
  for (int mi = 0; mi < MI; ++mi) {
#pragma unroll
    for (int ni = 0; ni < NI; ++ni) {
      int col = n0 + wn + ni * 16 + lq;
#pragma unroll
      for (int r = 0; r < 4; ++r) {
        int rowm = m0 + wm + mi * 16 + lg * 4 + r;
        if constexpr (OUT_F32)
          ((float*)C)[(size_t)rowm * ldc + col] = acc[mi][ni][r];
        else
          ((u16*)C)[(size_t)rowm * ldc + col] = (u16)f2bf(acc[mi][ni][r]);
      }
    }
  }
}

// ---------------- causal flash attention: in-block split-K, spill-free (R9) ----------------
__global__ __launch_bounds__(512, 4) void attn_kernel(const u16* __restrict__ q,
                                                      const u16* __restrict__ qpe,
                                                      const u16* __restrict__ kv,
                                                      const u16* __restrict__ kpe,
                                                      u16* __restrict__ o) {
  __shared__ u16 Ks[2][2][32 * 192];   // [buf][team] 12 KB each -> 48 KB
  __shared__ u16 Vs[2][2][32 * 128];   // [buf][team]  8 KB each -> 32 KB
  const int S = 1024;
  const int tid = threadIdx.x;
  const int w = tid >> 6, l = tid & 63;
  const int team = w >> 2, wt = w & 3;
  const int lq = l & 15, lg = l >> 4;
  const int h = blockIdx.y, b = blockIdx.z;
  const int chunk = b ? (15 - (int)blockIdx.x) : (int)blockIdx.x;
  const int q0 = chunk * 64 + wt * 16;
  const int nkt = chunk + 1;            // 32-row tiles per team
  const size_t qrow = (size_t)b * S + q0 + lq;

  short8 qf[6];
#pragma unroll
  for (int c = 0; c < 4; ++c)
    qf[c] = *(const short8*)(q + qrow * 3072 + h * 192 + c * 32 + lg * 8);
#pragma unroll
  for (int c = 0; c < 2; ++c)
    qf[4 + c] = *(const short8*)(qpe + (qrow * 16 + h) * 64 + c * 32 + lg * 8);

  const size_t gb = (size_t)b * S + 32 * team;   // team t starts at k-row 32t
  const u16* srcK[3]; int strK[3];
#pragma unroll
  for (int j = 0; j < 3; ++j) {
    int n = wt * 192 + j * 64 + l;         // K chunk id within team, 0..767
    int row = (n * 2731) >> 16;            // n / 24
    int pc = n - row * 24;
    int lc = (pc & ~7) | ((pc & 7) ^ (row & 7));   // inverse swizzle on source
    if (lc < 16) { srcK[j] = kv + (gb + row) * 4096 + h * 256 + lc * 8; strK[j] = 64 * 4096; }
    else         { srcK[j] = kpe + (gb + row) * 64 + (lc - 16) * 8;     strK[j] = 64 * 64; }
  }
  const u16* srcV[2];
#pragma unroll
  for (int j = 0; j < 2; ++j) {
    int n = wt * 128 + j * 64 + l;         // V chunk id within team, 0..511
    int dsub = n >> 6, m = n & 63;
    int ksub = m >> 3, r = (m >> 1) & 3, half = m & 1;
    srcV[j] = kv + (gb + ksub * 4 + r) * 4096 + h * 256 + 128 + dsub * 16 + half * 8;
  }

  auto stage = [&](int buf) {
#pragma unroll
    for (int j = 0; j < 3; ++j) {
      async_copy16(&Ks[buf][team][(wt * 192 + j * 64) * 8], srcK[j]);
      srcK[j] += strK[j];
    }
#pragma unroll
    for (int j = 0; j < 2; ++j) {
      async_copy16(&Vs[buf][team][(wt * 128 + j * 64) * 8], srcV[j]);
      srcV[j] += 64 * 4096;
    }
  };

  const float scl = 0.07216878364870323f * 1.4426950408889634f;  // 192^-0.5 * log2e
  float m2 = -INFINITY, lsum = 0.f;
  f32x4 oac[8];
#pragma unroll
  for (int dt = 0; dt < 8; ++dt) oac[dt] = (f32x4){0.f, 0.f, 0.f, 0.f};

  const int e0 = (lg ^ (lq & 7)) << 4;
  const int vbase = lg * 64 + lq * 4;

  stage(0);
  asm volatile("s_waitcnt vmcnt(0)" ::: "memory");
  __syncthreads();

  int buf = 0;
  for (int i = 0; i < nkt; ++i) {
    if (i + 1 < nkt) stage(buf ^ 1);
    const int kbase = (2 * i + team) * 32;

    if (kbase <= q0 + 15) {   // wave-uniform: skip fully-masked tiles
      const char* kb = (const char*)&Ks[buf][team][0];
      f32x4 sac0, sac1;
#pragma unroll
      for (int kt2 = 0; kt2 < 2; ++kt2) {
        int a0 = (kt2 * 16 + lq) * 384 + e0;
        int a1 = a0 ^ 64;
        f32x4 s = (f32x4){0.f, 0.f, 0.f, 0.f};
        s = mfma32(*(const short8*)(kb + a0),       qf[0], s);
        s = mfma32(*(const short8*)(kb + a1),       qf[1], s);
        s = mfma32(*(const short8*)(kb + a0 + 128), qf[2], s);
        s = mfma32(*(const short8*)(kb + a1 + 128), qf[3], s);
        s = mfma32(*(const short8*)(kb + a0 + 256), qf[4], s);
        s = mfma32(*(const short8*)(kb + a1 + 256), qf[5], s);
        if (kt2 == 0) sac0 = s; else sac1 = s;
      }

      const int qi = q0 + lq;
      const int kb0 = kbase + lg * 4;
      float s2[8];
#pragma unroll
      for (int r = 0; r < 4; ++r) {
        s2[r]     = (kb0 + r      <= qi) ? sac0[r] * scl : -INFINITY;
        s2[4 + r] = (kb0 + 16 + r <= qi) ? sac1[r] * scl : -INFINITY;
      }
      float mt = fmaxf(fmaxf(fmaxf(s2[0], s2[1]), fmaxf(s2[2], s2[3])),
                       fmaxf(fmaxf(s2[4], s2[5]), fmaxf(s2[6], s2[7])));
      mt = fmaxf(mt, __shfl_xor(mt, 16));
      mt = fmaxf(mt, __shfl_xor(mt, 32));
      float mnew = fmaxf(m2, mt);
      float resc = exp2f(m2 - mnew);
      float psum = 0.f;
#pragma unroll
      for (int r = 0; r < 8; ++r) { s2[r] = exp2f(s2[r] - mnew); psum += s2[r]; }
      psum += __shfl_xor(psum, 16);
      psum += __shfl_xor(psum, 32);
      lsum = lsum * resc + psum;
      m2 = mnew;
      short4v pf0, pf1;
#pragma unroll
      for (int r = 0; r < 4; ++r) { pf0[r] = f2bf(s2[r]); pf1[r] = f2bf(s2[4 + r]); }

      // ---- PV in 2 halves: vf[4][2] = 16 VGPRs peak ----
#pragma unroll
      for (int hf = 0; hf < 2; ++hf) {
        short4v vf[4][2];
#pragma unroll
        for (int dd = 0; dd < 4; ++dd)
#pragma unroll
          for (int kt2 = 0; kt2 < 2; ++kt2)
            vf[dd][kt2] = tr_read16(&Vs[buf][team][vbase + (hf * 4 + dd) * 512 + kt2 * 256]);
        asm volatile("s_waitcnt lgkmcnt(0)" ::: "memory");
        __builtin_amdgcn_sched_barrier(0);
#pragma unroll
        for (int dd = 0; dd < 4; ++dd) {
          const int dt = hf * 4 + dd;
          f32x4 t = oac[dt];
          t[0] *= resc; t[1] *= resc; t[2] *= resc; t[3] *= resc;
          t = mfma16(vf[dd][0], pf0, t);
          t = mfma16(vf[dd][1], pf1, t);
          oac[dt] = t;
        }
      }
    }

    asm volatile("s_waitcnt vmcnt(0)" ::: "memory");
    __syncthreads();
    buf ^= 1;
  }

  // ---- split-K merge via LDS (K/V buffers dead) ----
  float* MO = (float*)&Ks[0][0][0];     // 64 x 129 f32 (padded)
  float* MS = (float*)&Vs[0][0][0];     // 64 x 2 f32 stats
  const int qr = wt * 16 + lq;
  if (team == 1) {
#pragma unroll
    for (int dt = 0; dt < 8; ++dt)
#pragma unroll
      for (int r = 0; r < 4; ++r)
        MO[qr * 129 + dt * 16 + lg * 4 + r] = oac[dt][r];
    if (lg == 0) { MS[qr * 2] = m2; MS[qr * 2 + 1] = lsum; }
  }
  __syncthreads();
  if (team == 0) {
    float m1 = MS[qr * 2], l1 = MS[qr * 2 + 1];
    float mn = fmaxf(m2, m1);
    float a0 = exp2f(m2 - mn), a1 = exp2f(m1 - mn);
    float inv = 1.f / (lsum * a0 + l1 * a1);
#pragma unroll
    for (int dt = 0; dt < 8; ++dt)
#pragma unroll
      for (int r = 0; r < 4; ++r) {
        float val = (oac[dt][r] * a0 + MO[qr * 129 + dt * 16 + lg * 4 + r] * a1) * inv;
        o[((size_t)b * S + q0 + lq) * 2048 + h * 128 + dt * 16 + lg * 4 + r] = (u16)f2bf(val);
      }
  }
}

// ---------------- host launcher ----------------
extern "C" void kernel_launch(void* const* d_in, const int* in_sizes, int n_in,
                              void* d_out, int out_size, void* d_ws, size_t ws_size,
                              hipStream_t stream) {
  const float* h_in  = (const float*)d_in[0];
  const int*   pos   = (const int*)d_in[1];
  const float* qaw   = (const float*)d_in[2];
  const float* qaln  = (const float*)d_in[3];
  const float* qbw   = (const float*)d_in[4];
  const float* kvaw  = (const float*)d_in[5];
  const float* kvaln = (const float*)d_in[6];
  const float* kvbw  = (const float*)d_in[7];
  const float* ow    = (const float*)d_in[8];
  float* out = (float*)d_out;

  const int M = 2048;  // B*S
  char* p = (char*)d_ws;
  auto alloc = [&](size_t bytes) {
    char* r = p;
    p += (bytes + 255) & ~(size_t)255;
    return (u16*)r;
  };
  u16* h_bf   = alloc((size_t)M * 2048 * 2);       // hidden bf16; attno overlay later
  u16* Wfused = alloc((size_t)2112 * 2048 * 2);    // [q_a_w ; kv_a_w] rows, K=2048
  u16* Wqb    = alloc((size_t)3072 * 1536 * 2);
  u16* Wkvb   = alloc((size_t)4096 * 512 * 2);
  u16* OW     = alloc((size_t)2048 * 2048 * 2);    // o_w bf16 (dedicated, cast upfront)
  u16* F      = alloc((size_t)M * 2112 * 2);       // fused G1 out: q_a | ckv
  u16* qbuf   = alloc((size_t)M * 3072 * 2);
  u16* kvb    = alloc((size_t)M * 4096 * 2);
  u16* qpe    = alloc((size_t)M * 16 * 64 * 2);
  u16* kpe    = alloc((size_t)M * 64 * 2);
  // overlays (audited): Wfused dead after G1f -> qa/ckvn; h_bf dead -> attno.
  u16* qa    = Wfused;                             // M x 1536
  u16* ckvn  = Wfused + (size_t)1536 * 2048;       // M x 512
  u16* attno = h_bf;                               // M x 2048

  dim3 blk(256);

  // 1) ONE launch casts hidden + ALL weights (6 segments)
  cast6_kernel<<<19072, blk, 0, stream>>>(h_in, qaw, kvaw, qbw, kvbw, ow,
                                          h_bf, Wfused, Wfused + (size_t)1536 * 2048,
                                          Wqb, Wkvb, OW);

  // 2) fused G1+G3 (1-barrier, 3-buffer)
  gemm_bt3<128, 64, false, 1><<<dim3(33, 16), blk, 0, stream>>>(h_bf, Wfused, F, M, 2112, 2048, 2112);

  // 3) both RMSNorms in one launch
  rmsnorm2_kernel<<<4096, 192, 0, stream>>>(F, qaln, kvaln, qa, ckvn);

  // 4) G2 -> q (BN=96)
  gemm_bt<128, 96, false, 2><<<dim3(32, 16), blk, 0, stream>>>(qa, Wqb, qbuf, M, 3072, 1536, 3072);

  // 5) G4 -> kv (BN=128)
  gemm_bt<128, 128, false, 4><<<dim3(32, 16), blk, 0, stream>>>(ckvn, Wkvb, kvb, M, 4096, 512, 4096);

  // 6) RoPE
  rope_kernel<<<2048, 64, 0, stream>>>(qbuf, F + 1536, 2112, pos, qpe, kpe);

  // 7) attention
  attn_kernel<<<dim3(16, 16, 2), 512, 0, stream>>>(qbuf, qpe, kvb, kpe, attno);

  // 8) output projection (1-barrier, 3-buffer)
  gemm_bt3<128, 64, true, 5><<<dim3(32, 16), blk, 0, stream>>>(attno, OW, out, M, 2048, 2048, 2048);
}

// Round 18
// 166.700 us; speedup vs baseline: 1.1166x; 1.1143x over previous
//
#include <hip/hip_runtime.h>
#include <stdint.h>
#include <math.h>

typedef unsigned short u16;
typedef __attribute__((ext_vector_type(8))) short short8;   // 8 bf16 (4 VGPRs)
typedef __attribute__((ext_vector_type(4))) short short4v;  // 4 bf16 (2 VGPRs)
typedef __attribute__((ext_vector_type(4))) float f32x4;

#define DEVFN static __device__ __forceinline__

DEVFN float bf2f(short b) {
  union { unsigned int i; float f; } u;
  u.i = ((unsigned int)(unsigned short)b) << 16;
  return u.f;
}
DEVFN short f2bf(float f) {
  union { float f; unsigned int i; } u; u.f = f;
  unsigned int r = u.i + 0x7fffu + ((u.i >> 16) & 1u);  // RNE
  return (short)(r >> 16);
}

DEVFN f32x4 mfma32(short8 a, short8 b, f32x4 c) {
  return __builtin_amdgcn_mfma_f32_16x16x32_bf16(a, b, c, 0, 0, 0);
}
DEVFN f32x4 mfma16(short4v a, short4v b, f32x4 c) {
#if defined(__HIP_DEVICE_COMPILE__)
  return __builtin_amdgcn_mfma_f32_16x16x16bf16_1k(a, b, c, 0, 0, 0);
#else
  (void)a; (void)b; return c;  // host stub, never executed
#endif
}

typedef const __attribute__((address_space(1))) unsigned int* gp_t;
typedef __attribute__((address_space(3))) unsigned int* lp_t;
typedef const __attribute__((address_space(3))) u16* lds_cp;
DEVFN void async_copy16(u16* lds, const u16* g) {
  __builtin_amdgcn_global_load_lds((gp_t)(const void*)g, (lp_t)(void*)lds, 16, 0, 0);
}
// tr-read: 16-lane group reads a 4x16 bf16 row-major tile (128B); lane passes
// subtile_base + (lane&15)*8 bytes; output lane = column (lane&15), elem j = row j.
DEVFN short4v tr_read16(const u16* p) {
  short4v r;
  asm volatile("ds_read_b64_tr_b16 %0, %1" : "=v"(r) : "v"((lds_cp)(const void*)p));
  return r;
}
DEVFN void raw_barrier() {
  asm volatile("" ::: "memory");
  __builtin_amdgcn_s_barrier();
  asm volatile("" ::: "memory");
}

// ---------------- mega-cast: 6 f32 buffers -> bf16 in ONE launch ----------------
// f32x4 units: h_in 1048576 | qaw 786432 | kvaw 294912 | qbw 1179648 | kvbw 524288
// | ow 1048576; cum 1048576,1835008,2129920,3309568,3833856,4882432. grid 19072.
__global__ void cast6_kernel(const float* __restrict__ s0, const float* __restrict__ s1,
                             const float* __restrict__ s2, const float* __restrict__ s3,
                             const float* __restrict__ s4, const float* __restrict__ s5,
                             u16* __restrict__ d0, u16* __restrict__ d1,
                             u16* __restrict__ d2, u16* __restrict__ d3,
                             u16* __restrict__ d4, u16* __restrict__ d5) {
  int i = blockIdx.x * blockDim.x + threadIdx.x;
  const float* s; u16* d; int off;
  if (i < 1048576)      { s = s0; d = d0; off = 0; }
  else if (i < 1835008) { s = s1; d = d1; off = 1048576; }
  else if (i < 2129920) { s = s2; d = d2; off = 1835008; }
  else if (i < 3309568) { s = s3; d = d3; off = 2129920; }
  else if (i < 3833856) { s = s4; d = d4; off = 3309568; }
  else                  { s = s5; d = d5; off = 3833856; }
  int j = i - off;
  f32x4 v = ((const f32x4*)s)[j];
  short4v o;
  o[0] = f2bf(v[0]); o[1] = f2bf(v[1]); o[2] = f2bf(v[2]); o[3] = f2bf(v[3]);
  ((short4v*)d)[j] = o;
}

// ---------------- fused dual RMSNorm: q rows + kv rows in ONE launch ----------------
__global__ void rmsnorm2_kernel(const u16* __restrict__ F,
                                const float* __restrict__ qln,
                                const float* __restrict__ kvln,
                                u16* __restrict__ qa, u16* __restrict__ ckvn) {
  const int bid = blockIdx.x, t = threadIdx.x;
  const bool isQ = bid < 2048;
  const int row = isQ ? bid : bid - 2048;
  const u16* in = (isQ ? F : F + 1536) + (size_t)row * 2112;
  u16* out = isQ ? (qa + (size_t)row * 1536) : (ckvn + (size_t)row * 512);
  const float* w = isQ ? qln : kvln;
  const int len = isQ ? 1536 : 512;
  const int nact = len >> 3;
  float ss = 0.f;
  short8 v = {};
  if (t < nact) {
    v = *(const short8*)(in + t * 8);
#pragma unroll
    for (int j = 0; j < 8; ++j) { float x = bf2f(v[j]); ss += x * x; }
  }
#pragma unroll
  for (int off = 1; off < 64; off <<= 1) ss += __shfl_xor(ss, off);
  __shared__ float red[3];
  if ((t & 63) == 0) red[t >> 6] = ss;
  __syncthreads();
  ss = red[0] + red[1] + red[2];
  float r = rsqrtf(ss / (float)len + 1e-6f);
  if (t < nact) {
    const float* wp = w + t * 8;
    short8 ov;
#pragma unroll
    for (int j = 0; j < 8; ++j) ov[j] = f2bf(bf2f(v[j]) * r * wp[j]);
    *(short8*)(out + t * 8) = ov;
  }
}

// ---------------- RoPE (interleaved-perm variant) ----------------
__global__ void rope_kernel(const u16* __restrict__ q, const u16* __restrict__ ckv,
                            int cstride,
                            const int* __restrict__ pos_ids,
                            u16* __restrict__ qpe, u16* __restrict__ kpe) {
  const int row = blockIdx.x;
  const int t = threadIdx.x;
  const float pos = (float)pos_ids[row];
  const float L2TH = 13.287712379549449f;  // log2(10000)
  if (t < 32) {
    int i = t;
    float inv = exp2f(-L2TH * (float)i / 32.0f);
    float sv, cv; sincosf(pos * inv, &sv, &cv);
    float x0 = bf2f(ckv[(size_t)row * cstride + 512 + 2 * i]);
    float x1 = bf2f(ckv[(size_t)row * cstride + 512 + 2 * i + 1]);
    kpe[(size_t)row * 64 + i]      = (u16)f2bf(x0 * cv - x1 * sv);
    kpe[(size_t)row * 64 + 32 + i] = (u16)f2bf(x1 * cv + x0 * sv);
  }
#pragma unroll
  for (int j = 0; j < 8; ++j) {
    int idx = t + 64 * j;
    int hh = idx >> 5, i = idx & 31;
    float inv = exp2f(-L2TH * (float)i / 32.0f);
    float sv, cv; sincosf(pos * inv, &sv, &cv);
    const u16* base = q + (size_t)row * 3072 + hh * 192 + 128;
    float x0 = bf2f(base[2 * i]), x1 = bf2f(base[2 * i + 1]);
    u16* ob = qpe + ((size_t)row * 16 + hh) * 64;
    ob[i]      = (u16)f2bf(x0 * cv - x1 * sv);
    ob[32 + i] = (u16)f2bf(x1 * cv + x0 * sv);
  }
}

// ---------------- GEMM: C[m,n] = sum_k A[m,k]*B[n,k], bf16 in, f32 acc ----------------
// 2-barrier, 2-buffer, T4 counted-vmcnt, prefetch DISTANCE 2, XCD swizzle —
// the only verified-fast pipeline shape this session:
//  - R14: stage between waitcnt and ds_reads -> compiler vmcnt(0) drain, 2x slower.
//  - R17: distance-1 (stage(t+1) right before waiting t) -> HBM latency exposed
//    on streaming operands (G1f 31->51 us). Distance-2 with stage at END of the
//    iteration (after second barrier) covers ~2 compute phases > 900 cy HBM.
template <int BM, int BN, bool OUT_F32, int TAG>
__global__ __launch_bounds__(256) void gemm_bt(const u16* __restrict__ A,
                                               const u16* __restrict__ B,
                                               void* __restrict__ C,
                                               int M, int N, int K, int ldc) {
  constexpr int ACH = BM / 32;
  constexpr int BCH = BN / 32;
  constexpr int MI  = BM / 32;
  constexpr int NI  = BN / 32;
  constexpr int LOADS = ACH + BCH;
  __shared__ u16 As[2][BM * 64];
  __shared__ u16 Bs[2][BN * 64];
  const int tid = threadIdx.x;
  const int w = tid >> 6, l = tid & 63;
  const int lq = l & 15, lg = l >> 4;
  const int wm = (w >> 1) * (BM / 2);
  const int wn = (w & 1) * (BN / 2);

  const int f = blockIdx.x + gridDim.x * blockIdx.y;
  const int nwg = gridDim.x * gridDim.y;
  const int swz = (f & 7) * (nwg >> 3) + (f >> 3);
  const int bx = swz % gridDim.x, by = swz / gridDim.x;
  const int m0 = by * BM, n0 = bx * BN;

  const u16* srcA[ACH]; int dstA[ACH];
#pragma unroll
  for (int i = 0; i < ACH; ++i) {
    int c = i * 256 + tid;
    int row = c >> 3, pc = c & 7;
    int lc = pc ^ (row & 7);
    srcA[i] = A + (size_t)(m0 + row) * K + lc * 8;
    dstA[i] = c * 8;
  }
  const u16* srcB[BCH]; int dstB[BCH];
#pragma unroll
  for (int i = 0; i < BCH; ++i) {
    int c = i * 256 + tid;
    int row = c >> 3, pc = c & 7;
    int lc = pc ^ (row & 7);
    srcB[i] = B + (size_t)(n0 + row) * K + lc * 8;
    dstB[i] = c * 8;
  }

  auto stage = [&](int buf) {
#pragma unroll
    for (int i = 0; i < ACH; ++i) {
      async_copy16(&As[buf][dstA[i]], srcA[i]);
      srcA[i] += 64;
    }
#pragma unroll
    for (int i = 0; i < BCH; ++i) {
      async_copy16(&Bs[buf][dstB[i]], srcB[i]);
      srcB[i] += 64;
    }
  };

  f32x4 acc[MI][NI];
#pragma unroll
  for (int i = 0; i < MI; ++i)
#pragma unroll
    for (int j = 0; j < NI; ++j) acc[i][j] = (f32x4){0.f, 0.f, 0.f, 0.f};

  const int nt = K >> 6;
  stage(0);
  if (nt > 1) stage(1);

  for (int t = 0; t < nt; ++t) {
    if (t + 1 < nt) {
      if constexpr (LOADS == 4)      asm volatile("s_waitcnt vmcnt(4)" ::: "memory");
      else if constexpr (LOADS == 6) asm volatile("s_waitcnt vmcnt(6)" ::: "memory");
      else if constexpr (LOADS == 7) asm volatile("s_waitcnt vmcnt(7)" ::: "memory");
      else                           asm volatile("s_waitcnt vmcnt(8)" ::: "memory");
    } else {
      asm volatile("s_waitcnt vmcnt(0)" ::: "memory");
    }
    raw_barrier();

    const int buf = t & 1;
#pragma unroll
    for (int ks = 0; ks < 2; ++ks) {
      short8 af[MI], bfr[NI];
#pragma unroll
      for (int mi = 0; mi < MI; ++mi) {
        int row = wm + mi * 16 + lq;
        int ch = ((ks << 2) | lg) ^ (row & 7);
        af[mi] = *(const short8*)&As[buf][row * 64 + ch * 8];
      }
#pragma unroll
      for (int ni = 0; ni < NI; ++ni) {
        int row = wn + ni * 16 + lq;
        int ch = ((ks << 2) | lg) ^ (row & 7);
        bfr[ni] = *(const short8*)&Bs[buf][row * 64 + ch * 8];
      }
#pragma unroll
      for (int mi = 0; mi < MI; ++mi)
#pragma unroll
        for (int ni = 0; ni < NI; ++ni)
          acc[mi][ni] = mfma32(af[mi], bfr[ni], acc[mi][ni]);
    }

    raw_barrier();
    if (t + 2 < nt) stage(buf);   // distance-2, END of iter (R14/R17 lessons)
  }

#pragma unroll
  for (int mi = 0; mi < MI; ++mi) {
#pragma unroll
    for (int ni = 0; ni < NI; ++ni) {
      int col = n0 + wn + ni * 16 + lq;
#pragma unroll
      for (int r = 0; r < 4; ++r) {
        int rowm = m0 + wm + mi * 16 + lg * 4 + r;
        if constexpr (OUT_F32)
          ((float*)C)[(size_t)rowm * ldc + col] = acc[mi][ni][r];
        else
          ((u16*)C)[(size_t)rowm * ldc + col] = (u16)f2bf(acc[mi][ni][r]);
      }
    }
  }
}

// ---------------- causal flash attention: in-block split-K, spill-free (R9) ----------------
__global__ __launch_bounds__(512, 4) void attn_kernel(const u16* __restrict__ q,
                                                      const u16* __restrict__ qpe,
                                                      const u16* __restrict__ kv,
                                                      const u16* __restrict__ kpe,
                                                      u16* __restrict__ o) {
  __shared__ u16 Ks[2][2][32 * 192];   // [buf][team] 12 KB each -> 48 KB
  __shared__ u16 Vs[2][2][32 * 128];   // [buf][team]  8 KB each -> 32 KB
  const int S = 1024;
  const int tid = threadIdx.x;
  const int w = tid >> 6, l = tid & 63;
  const int team = w >> 2, wt = w & 3;
  const int lq = l & 15, lg = l >> 4;
  const int h = blockIdx.y, b = blockIdx.z;
  const int chunk = b ? (15 - (int)blockIdx.x) : (int)blockIdx.x;
  const int q0 = chunk * 64 + wt * 16;
  const int nkt = chunk + 1;            // 32-row tiles per team
  const size_t qrow = (size_t)b * S + q0 + lq;

  short8 qf[6];
#pragma unroll
  for (int c = 0; c < 4; ++c)
    qf[c] = *(const short8*)(q + qrow * 3072 + h * 192 + c * 32 + lg * 8);
#pragma unroll
  for (int c = 0; c < 2; ++c)
    qf[4 + c] = *(const short8*)(qpe + (qrow * 16 + h) * 64 + c * 32 + lg * 8);

  const size_t gb = (size_t)b * S + 32 * team;   // team t starts at k-row 32t
  const u16* srcK[3]; int strK[3];
#pragma unroll
  for (int j = 0; j < 3; ++j) {
    int n = wt * 192 + j * 64 + l;         // K chunk id within team, 0..767
    int row = (n * 2731) >> 16;            // n / 24
    int pc = n - row * 24;
    int lc = (pc & ~7) | ((pc & 7) ^ (row & 7));   // inverse swizzle on source
    if (lc < 16) { srcK[j] = kv + (gb + row) * 4096 + h * 256 + lc * 8; strK[j] = 64 * 4096; }
    else         { srcK[j] = kpe + (gb + row) * 64 + (lc - 16) * 8;     strK[j] = 64 * 64; }
  }
  const u16* srcV[2];
#pragma unroll
  for (int j = 0; j < 2; ++j) {
    int n = wt * 128 + j * 64 + l;         // V chunk id within team, 0..511
    int dsub = n >> 6, m = n & 63;
    int ksub = m >> 3, r = (m >> 1) & 3, half = m & 1;
    srcV[j] = kv + (gb + ksub * 4 + r) * 4096 + h * 256 + 128 + dsub * 16 + half * 8;
  }

  auto stage = [&](int buf) {
#pragma unroll
    for (int j = 0; j < 3; ++j) {
      async_copy16(&Ks[buf][team][(wt * 192 + j * 64) * 8], srcK[j]);
      srcK[j] += strK[j];
    }
#pragma unroll
    for (int j = 0; j < 2; ++j) {
      async_copy16(&Vs[buf][team][(wt * 128 + j * 64) * 8], srcV[j]);
      srcV[j] += 64 * 4096;
    }
  };

  const float scl = 0.07216878364870323f * 1.4426950408889634f;  // 192^-0.5 * log2e
  float m2 = -INFINITY, lsum = 0.f;
  f32x4 oac[8];
#pragma unroll
  for (int dt = 0; dt < 8; ++dt) oac[dt] = (f32x4){0.f, 0.f, 0.f, 0.f};

  const int e0 = (lg ^ (lq & 7)) << 4;
  const int vbase = lg * 64 + lq * 4;

  stage(0);
  asm volatile("s_waitcnt vmcnt(0)" ::: "memory");
  __syncthreads();

  int buf = 0;
  for (int i = 0; i < nkt; ++i) {
    if (i + 1 < nkt) stage(buf ^ 1);
    const int kbase = (2 * i + team) * 32;

    if (kbase <= q0 + 15) {   // wave-uniform: skip fully-masked tiles
      const char* kb = (const char*)&Ks[buf][team][0];
      f32x4 sac0, sac1;
#pragma unroll
      for (int kt2 = 0; kt2 < 2; ++kt2) {
        int a0 = (kt2 * 16 + lq) * 384 + e0;
        int a1 = a0 ^ 64;
        f32x4 s = (f32x4){0.f, 0.f, 0.f, 0.f};
        s = mfma32(*(const short8*)(kb + a0),       qf[0], s);
        s = mfma32(*(const short8*)(kb + a1),       qf[1], s);
        s = mfma32(*(const short8*)(kb + a0 + 128), qf[2], s);
        s = mfma32(*(const short8*)(kb + a1 + 128), qf[3], s);
        s = mfma32(*(const short8*)(kb + a0 + 256), qf[4], s);
        s = mfma32(*(const short8*)(kb + a1 + 256), qf[5], s);
        if (kt2 == 0) sac0 = s; else sac1 = s;
      }

      const int qi = q0 + lq;
      const int kb0 = kbase + lg * 4;
      float s2[8];
#pragma unroll
      for (int r = 0; r < 4; ++r) {
        s2[r]     = (kb0 + r      <= qi) ? sac0[r] * scl : -INFINITY;
        s2[4 + r] = (kb0 + 16 + r <= qi) ? sac1[r] * scl : -INFINITY;
      }
      float mt = fmaxf(fmaxf(fmaxf(s2[0], s2[1]), fmaxf(s2[2], s2[3])),
                       fmaxf(fmaxf(s2[4], s2[5]), fmaxf(s2[6], s2[7])));
      mt = fmaxf(mt, __shfl_xor(mt, 16));
      mt = fmaxf(mt, __shfl_xor(mt, 32));
      float mnew = fmaxf(m2, mt);
      float resc = exp2f(m2 - mnew);
      float psum = 0.f;
#pragma unroll
      for (int r = 0; r < 8; ++r) { s2[r] = exp2f(s2[r] - mnew); psum += s2[r]; }
      psum += __shfl_xor(psum, 16);
      psum += __shfl_xor(psum, 32);
      lsum = lsum * resc + psum;
      m2 = mnew;
      short4v pf0, pf1;
#pragma unroll
      for (int r = 0; r < 4; ++r) { pf0[r] = f2bf(s2[r]); pf1[r] = f2bf(s2[4 + r]); }

      // ---- PV in 2 halves: vf[4][2] = 16 VGPRs peak ----
#pragma unroll
      for (int hf = 0; hf < 2; ++hf) {
        short4v vf[4][2];
#pragma unroll
        for (int dd = 0; dd < 4; ++dd)
#pragma unroll
          for (int kt2 = 0; kt2 < 2; ++kt2)
            vf[dd][kt2] = tr_read16(&Vs[buf][team][vbase + (hf * 4 + dd) * 512 + kt2 * 256]);
        asm volatile("s_waitcnt lgkmcnt(0)" ::: "memory");
        __builtin_amdgcn_sched_barrier(0);
#pragma unroll
        for (int dd = 0; dd < 4; ++dd) {
          const int dt = hf * 4 + dd;
          f32x4 t = oac[dt];
          t[0] *= resc; t[1] *= resc; t[2] *= resc; t[3] *= resc;
          t = mfma16(vf[dd][0], pf0, t);
          t = mfma16(vf[dd][1], pf1, t);
          oac[dt] = t;
        }
      }
    }

    asm volatile("s_waitcnt vmcnt(0)" ::: "memory");
    __syncthreads();
    buf ^= 1;
  }

  // ---- split-K merge via LDS (K/V buffers dead) ----
  float* MO = (float*)&Ks[0][0][0];     // 64 x 129 f32 (padded)
  float* MS = (float*)&Vs[0][0][0];     // 64 x 2 f32 stats
  const int qr = wt * 16 + lq;
  if (team == 1) {
#pragma unroll
    for (int dt = 0; dt < 8; ++dt)
#pragma unroll
      for (int r = 0; r < 4; ++r)
        MO[qr * 129 + dt * 16 + lg * 4 + r] = oac[dt][r];
    if (lg == 0) { MS[qr * 2] = m2; MS[qr * 2 + 1] = lsum; }
  }
  __syncthreads();
  if (team == 0) {
    float m1 = MS[qr * 2], l1 = MS[qr * 2 + 1];
    float mn = fmaxf(m2, m1);
    float a0 = exp2f(m2 - mn), a1 = exp2f(m1 - mn);
    float inv = 1.f / (lsum * a0 + l1 * a1);
#pragma unroll
    for (int dt = 0; dt < 8; ++dt)
#pragma unroll
      for (int r = 0; r < 4; ++r) {
        float val = (oac[dt][r] * a0 + MO[qr * 129 + dt * 16 + lg * 4 + r] * a1) * inv;
        o[((size_t)b * S + q0 + lq) * 2048 + h * 128 + dt * 16 + lg * 4 + r] = (u16)f2bf(val);
      }
  }
}

// ---------------- host launcher ----------------
extern "C" void kernel_launch(void* const* d_in, const int* in_sizes, int n_in,
                              void* d_out, int out_size, void* d_ws, size_t ws_size,
                              hipStream_t stream) {
  const float* h_in  = (const float*)d_in[0];
  const int*   pos   = (const int*)d_in[1];
  const float* qaw   = (const float*)d_in[2];
  const float* qaln  = (const float*)d_in[3];
  const float* qbw   = (const float*)d_in[4];
  const float* kvaw  = (const float*)d_in[5];
  const float* kvaln = (const float*)d_in[6];
  const float* kvbw  = (const float*)d_in[7];
  const float* ow    = (const float*)d_in[8];
  float* out = (float*)d_out;

  const int M = 2048;  // B*S
  char* p = (char*)d_ws;
  auto alloc = [&](size_t bytes) {
    char* r = p;
    p += (bytes + 255) & ~(size_t)255;
    return (u16*)r;
  };
  u16* h_bf   = alloc((size_t)M * 2048 * 2);       // hidden bf16; attno overlay later
  u16* Wfused = alloc((size_t)2112 * 2048 * 2);    // [q_a_w ; kv_a_w] rows, K=2048
  u16* Wqb    = alloc((size_t)3072 * 1536 * 2);
  u16* Wkvb   = alloc((size_t)4096 * 512 * 2);
  u16* OW     = alloc((size_t)2048 * 2048 * 2);    // o_w bf16 (dedicated, cast upfront)
  u16* F      = alloc((size_t)M * 2112 * 2);       // fused G1 out: q_a | ckv
  u16* qbuf   = alloc((size_t)M * 3072 * 2);
  u16* kvb    = alloc((size_t)M * 4096 * 2);
  u16* qpe    = alloc((size_t)M * 16 * 64 * 2);
  u16* kpe    = alloc((size_t)M * 64 * 2);
  // overlays (audited): Wfused dead after G1f -> qa/ckvn; h_bf dead -> attno.
  u16* qa    = Wfused;                             // M x 1536
  u16* ckvn  = Wfused + (size_t)1536 * 2048;       // M x 512
  u16* attno = h_bf;                               // M x 2048

  dim3 blk(256);

  // 1) ONE launch casts hidden + ALL weights (6 segments)
  cast6_kernel<<<19072, blk, 0, stream>>>(h_in, qaw, kvaw, qbw, kvbw, ow,
                                          h_bf, Wfused, Wfused + (size_t)1536 * 2048,
                                          Wqb, Wkvb, OW);

  // 2) fused G1+G3 (2-barrier, distance-2 — the proven template)
  gemm_bt<128, 64, false, 1><<<dim3(33, 16), blk, 0, stream>>>(h_bf, Wfused, F, M, 2112, 2048, 2112);

  // 3) both RMSNorms in one launch
  rmsnorm2_kernel<<<4096, 192, 0, stream>>>(F, qaln, kvaln, qa, ckvn);

  // 4) G2 -> q (BN=96)
  gemm_bt<128, 96, false, 2><<<dim3(32, 16), blk, 0, stream>>>(qa, Wqb, qbuf, M, 3072, 1536, 3072);

  // 5) G4 -> kv (BN=128)
  gemm_bt<128, 128, false, 4><<<dim3(32, 16), blk, 0, stream>>>(ckvn, Wkvb, kvb, M, 4096, 512, 4096);

  // 6) RoPE
  rope_kernel<<<2048, 64, 0, stream>>>(qbuf, F + 1536, 2112, pos, qpe, kpe);

  // 7) attention
  attn_kernel<<<dim3(16, 16, 2), 512, 0, stream>>>(qbuf, qpe, kvb, kpe, attno);

  // 8) output projection (2-barrier)
  gemm_bt<128, 64, true, 5><<<dim3(32, 16), blk, 0, stream>>>(attno, OW, out, M, 2048, 2048, 2048);
}